// Round 16
// baseline (1000.122 us; speedup 1.0000x reference)
//
#include <hip/hip_runtime.h>
#include <hip/hip_bf16.h>

constexpr int K_MAX    = 128;   // max supported k (actual k=64 read from device)
constexpr int S_MAX    = 128;   // sure-member cap per row (provably S <= k-1 < 128)
constexpr int A_MAX    = 256;   // ambiguous cap per row
constexpr int CAND_MAX = 512;   // fallback candidate cap
constexpr int BM = 128, BN = 128, BKF = 16;
constexpr int NBITER = 42;      // fallback bisection iterations
constexpr int D_MAX   = 2048;   // fast path requires D <= D_MAX
constexpr int H_FIX   = 16384;  // fast path requires H == H_FIX

typedef __attribute__((ext_vector_type(8))) short bf16x8;
typedef __attribute__((ext_vector_type(8))) unsigned short u16x8;
typedef __attribute__((ext_vector_type(4))) float f32x4;

__device__ inline unsigned short f2bf(float f) {   // round-to-nearest-even
  unsigned u = __float_as_uint(f);
  return (unsigned short)((u + 0x7fff + ((u >> 16) & 1)) >> 16);
}
// monotone 16-bit key: key order == value order (handles negatives)
__device__ inline unsigned short key_of(float f) {
  unsigned short b = f2bf(f);
  return b ^ ((b & 0x8000) ? 0xFFFF : 0x8000);
}
__device__ inline float val_of_key(unsigned short kk) {
  unsigned short b = (kk & 0x8000) ? (unsigned short)(kk ^ 0x8000)
                                   : (unsigned short)(kk ^ 0xFFFF);
  return __uint_as_float(((unsigned)b) << 16);
}
__device__ inline float bf2f(unsigned short b) {
  return __uint_as_float(((unsigned)b) << 16);
}

// conflict-free superrow swizzle (R8-verified: bank conflicts 1.26e8 -> 0)
__device__ inline int lds_slot(int r, int c) {
  return ((r >> 1) << 4) | ((r & 1) << 3) | (c ^ ((r >> 1) & 7));
}

// ---------------- prep: Xb = bf16(x - b_pre), Wb = bf16(W_enc) ----------------
__global__ __launch_bounds__(256) void prep_xb(
    const float* __restrict__ x, const float* __restrict__ b_pre,
    unsigned short* __restrict__ Xb, int D, size_t total4)
{
  for (size_t i = blockIdx.x * 256 + threadIdx.x; i < total4; i += (size_t)gridDim.x * 256) {
    const size_t e = i * 4;
    const int d = (int)(e % D);
    float4 xv = *reinterpret_cast<const float4*>(x + e);
    float4 bp = *reinterpret_cast<const float4*>(b_pre + d);
    ushort4 o;
    o.x = f2bf(xv.x - bp.x); o.y = f2bf(xv.y - bp.y);
    o.z = f2bf(xv.z - bp.z); o.w = f2bf(xv.w - bp.w);
    *reinterpret_cast<ushort4*>(Xb + e) = o;
  }
}

__global__ __launch_bounds__(256) void prep_wb(
    const float* __restrict__ W, unsigned short* __restrict__ Wb, size_t total4)
{
  for (size_t i = blockIdx.x * 256 + threadIdx.x; i < total4; i += (size_t)gridDim.x * 256) {
    const size_t e = i * 4;
    float4 wv = *reinterpret_cast<const float4*>(W + e);
    ushort4 o;
    o.x = f2bf(wv.x); o.y = f2bf(wv.y); o.z = f2bf(wv.z); o.w = f2bf(wv.w);
    *reinterpret_cast<ushort4*>(Wb + e) = o;
  }
}

// ---------------- kernel 1: encoder GEMM 256x256, 8 waves, 4-phase counted-vmcnt ----------------
// (R11/R13-verified K-loop: MfmaUtil ~44%.) Per-wave 64(M)x128(N). K-tile=64.
// R16: keys go to each hidden row's SECOND half (H u16 = half the f32 row);
// epilogue also zero-fills this block's share of the FIRST half (cols n0/2..n0/2+127)
// -- moves 256MB of the mandatory zero under the compute-bound GEMM for free.
__global__ __launch_bounds__(512, 2) void enc_gemm_bf16(
    const unsigned short* __restrict__ Xb, const unsigned short* __restrict__ Wb,
    const float* __restrict__ b_enc, float* __restrict__ pre, int D, int H)
{
  __shared__ unsigned short As[2][2048 * 8];
  __shared__ unsigned short Bs[2][2048 * 8];
  const int tid  = threadIdx.x;
  const int wave = tid >> 6, lane = tid & 63;
  const int m0 = blockIdx.y * 256, n0 = blockIdx.x * 256;
  const int wm = (wave >> 1) * 64;
  const int wn = (wave & 1) * 128;
  const int l16 = lane & 15, lhi = lane >> 4;

  f32x4 acc[4][8];
#pragma unroll
  for (int i = 0; i < 4; ++i)
#pragma unroll
    for (int j = 0; j < 8; ++j) acc[i][j] = (f32x4){0.f, 0.f, 0.f, 0.f};

  const int NT = D / 64;

  auto stageA = [&](int buf, int h, int kb) {
#pragma unroll
    for (int i = 0; i < 2; ++i) {
      const int idx = i * 512 + wave * 64 + lane;
      const int sr = idx >> 4, u = idx & 15;
      const int r  = (sr << 1) | (u >> 3);
      const int ch = (u & 7) ^ (sr & 7);
      __builtin_amdgcn_global_load_lds(
          (const __attribute__((address_space(1))) unsigned int*)
              (Xb + (size_t)(m0 + h * 128 + r) * D + kb + ch * 8),
          (__attribute__((address_space(3))) unsigned int*)
              (&As[buf][(size_t)(h * 1024 + idx) * 8]), 16, 0, 0);
    }
  };
  auto stageBq = [&](int buf, int q, int kb) {
    const int s  = (q & 1) * 512 + wave * 64 + lane;
    const int sr = s >> 4, u = s & 15;
    const int r  = (sr << 1) | (u >> 3);
    const int ch = (u & 7) ^ (sr & 7);
    __builtin_amdgcn_global_load_lds(
        (const __attribute__((address_space(1))) unsigned int*)
            (Wb + (size_t)(n0 + (q >> 1) * 128 + r) * D + kb + ch * 8),
        (__attribute__((address_space(3))) unsigned int*)
            (&Bs[buf][(size_t)((q >> 1) * 1024 + s) * 8]), 16, 0, 0);
  };
  auto readA = [&](int buf, int mi, int kk) -> bf16x8 {
    const int gr = wm + mi * 16 + l16;
    return *reinterpret_cast<const bf16x8*>(
        &As[buf][(size_t)((gr >> 7) * 1024 + lds_slot(gr & 127, kk * 4 + lhi)) * 8]);
  };
  auto readB = [&](int buf, int ni, int kk) -> bf16x8 {
    const int gr = wn + ni * 16 + l16;
    return *reinterpret_cast<const bf16x8*>(
        &Bs[buf][(size_t)((gr >> 7) * 1024 + lds_slot(gr & 127, kk * 4 + lhi)) * 8]);
  };

  stageA(0, 0, 0); stageA(0, 1, 0);
  stageBq(0, 0, 0); stageBq(0, 2, 0);
  stageBq(0, 1, 0); stageBq(0, 3, 0);

  int cur = 0;
  for (int t = 0; t < NT; ++t) {
    const int nxt = cur ^ 1;
    const int kb1 = (t + 1) * 64;
    const bool more = (t + 1 < NT);

    bf16x8 af[4][2], bf[2][2];

    asm volatile("s_waitcnt vmcnt(2)" ::: "memory");
    __builtin_amdgcn_s_barrier();
#pragma unroll
    for (int mi = 0; mi < 4; ++mi)
#pragma unroll
      for (int kk = 0; kk < 2; ++kk) af[mi][kk] = readA(cur, mi, kk);
#pragma unroll
    for (int j = 0; j < 2; ++j)
#pragma unroll
      for (int kk = 0; kk < 2; ++kk) bf[j][kk] = readB(cur, j, kk);
    if (more) stageA(nxt, 0, kb1);
    __builtin_amdgcn_s_setprio(1);
#pragma unroll
    for (int mi = 0; mi < 4; ++mi)
#pragma unroll
      for (int j = 0; j < 2; ++j)
#pragma unroll
        for (int kk = 0; kk < 2; ++kk)
          acc[mi][j] = __builtin_amdgcn_mfma_f32_16x16x32_bf16(af[mi][kk], bf[j][kk], acc[mi][j], 0, 0, 0);
    __builtin_amdgcn_s_setprio(0);

#pragma unroll
    for (int j = 0; j < 2; ++j)
#pragma unroll
      for (int kk = 0; kk < 2; ++kk) bf[j][kk] = readB(cur, 2 + j, kk);
    if (more) stageA(nxt, 1, kb1);
    __builtin_amdgcn_s_setprio(1);
#pragma unroll
    for (int mi = 0; mi < 4; ++mi)
#pragma unroll
      for (int j = 0; j < 2; ++j)
#pragma unroll
        for (int kk = 0; kk < 2; ++kk)
          acc[mi][2 + j] = __builtin_amdgcn_mfma_f32_16x16x32_bf16(af[mi][kk], bf[j][kk], acc[mi][2 + j], 0, 0, 0);
    __builtin_amdgcn_s_setprio(0);

    if (more) { asm volatile("s_waitcnt vmcnt(4)" ::: "memory"); }
    else      { asm volatile("s_waitcnt vmcnt(0)" ::: "memory"); }
    __builtin_amdgcn_s_barrier();
#pragma unroll
    for (int j = 0; j < 2; ++j)
#pragma unroll
      for (int kk = 0; kk < 2; ++kk) bf[j][kk] = readB(cur, 4 + j, kk);
    if (more) { stageBq(nxt, 0, kb1); stageBq(nxt, 2, kb1); }
    __builtin_amdgcn_s_setprio(1);
#pragma unroll
    for (int mi = 0; mi < 4; ++mi)
#pragma unroll
      for (int j = 0; j < 2; ++j)
#pragma unroll
        for (int kk = 0; kk < 2; ++kk)
          acc[mi][4 + j] = __builtin_amdgcn_mfma_f32_16x16x32_bf16(af[mi][kk], bf[j][kk], acc[mi][4 + j], 0, 0, 0);
    __builtin_amdgcn_s_setprio(0);

#pragma unroll
    for (int j = 0; j < 2; ++j)
#pragma unroll
      for (int kk = 0; kk < 2; ++kk) bf[j][kk] = readB(cur, 6 + j, kk);
    if (more) { stageBq(nxt, 1, kb1); stageBq(nxt, 3, kb1); }
    __builtin_amdgcn_s_setprio(1);
#pragma unroll
    for (int mi = 0; mi < 4; ++mi)
#pragma unroll
      for (int j = 0; j < 2; ++j)
#pragma unroll
        for (int kk = 0; kk < 2; ++kk)
          acc[mi][6 + j] = __builtin_amdgcn_mfma_f32_16x16x32_bf16(af[mi][kk], bf[j][kk], acc[mi][6 + j], 0, 0, 0);
    __builtin_amdgcn_s_setprio(0);

    cur = nxt;
  }

  // epilogue A: zero this block's share of the hidden first half
  // (rows m0..m0+255, f32 cols [n0/2, n0/2+128) -- disjoint across bx blocks)
  {
    const int zc0 = n0 >> 1;
    const f32x4 z4 = (f32x4){0.f, 0.f, 0.f, 0.f};
#pragma unroll
    for (int i = 0; i < 16; ++i) {
      const int idx = i * 512 + tid;       // 0..8191 = 256 rows x 32 chunks
      const int row = idx >> 5;
      const int c4  = idx & 31;
      *reinterpret_cast<f32x4*>(pre + (size_t)(m0 + row) * H + zc0 + c4 * 4) = z4;
    }
  }

  // epilogue B: write monotone u16 keys into each row's SECOND half
#pragma unroll
  for (int ni = 0; ni < 8; ++ni) {
    const int n = n0 + wn + ni * 16 + l16;
    const float be = b_enc[n];
#pragma unroll
    for (int mi = 0; mi < 4; ++mi) {
      const int mbase = m0 + wm + mi * 16 + lhi * 4;
#pragma unroll
      for (int r = 0; r < 4; ++r) {
        unsigned short* prow = (unsigned short*)(pre + (size_t)(mbase + r) * H + (H >> 1));
        prow[n] = key_of(acc[mi][ni][r] + be);
      }
    }
  }
}

// ---------------- kernel 2: key classify; zeroes only its row's SECOND half ----------------
__global__ __launch_bounds__(256) void topk_classify_keys(
    float* __restrict__ hidden,
    int* __restrict__ sure_ix, float* __restrict__ sure_val, int* __restrict__ sure_cnt,
    int* __restrict__ amb_ix, int* __restrict__ amb_cnt,
    const int* __restrict__ kptr, float delta)
{
  constexpr int H = H_FIX, NC = H_FIX / (256 * 8);
  __shared__ int hist[4096];
  __shared__ int chunk[256];
  __shared__ int misc[8];

  const int tid = threadIdx.x, b = blockIdx.x;
  const int k = min(*kptr, K_MAX);
  float* hrow = hidden + (size_t)b * H;
  const unsigned short* krow = (const unsigned short*)(hrow + (H >> 1));

  if (tid < 8) misc[tid] = 0;
  for (int i = tid; i < 4096; i += 256) hist[i] = 0;

  u16x8 kv[NC];
#pragma unroll
  for (int i = 0; i < NC; ++i)
    kv[i] = *reinterpret_cast<const u16x8*>(krow + ((size_t)i * 256 + tid) * 8);
  __syncthreads();   // keys in registers before their region is overwritten

  // zero the second half of the row (first half was zeroed by the GEMM)
  const float4 z4 = {0.f, 0.f, 0.f, 0.f};
  float4* z2 = reinterpret_cast<float4*>(hrow + (H >> 1));
  for (int i = tid; i < (H >> 3); i += 256) z2[i] = z4;

#pragma unroll
  for (int i = 0; i < NC; ++i)
#pragma unroll
    for (int j = 0; j < 8; ++j)
      atomicAdd(&hist[((unsigned)(unsigned short)kv[i][j]) >> 4], 1);
  __syncthreads();

  int csum = 0;
#pragma unroll
  for (int j = 0; j < 16; ++j) csum += hist[tid * 16 + j];
  chunk[tid] = csum;
  __syncthreads();
  int gt = 0;
  for (int j = tid + 1; j < 256; ++j) gt += chunk[j];
  {
    int run = gt;
#pragma unroll
    for (int j = 15; j >= 0; --j) {
      const int hc = hist[tid * 16 + j];
      if (run < k && k <= run + hc) { misc[0] = tid * 16 + j; misc[1] = run; }
      run += hc;
    }
  }
  __syncthreads();
  const int b1 = misc[0];
  if (tid < 16) chunk[tid] = 0;
  __syncthreads();
#pragma unroll
  for (int i = 0; i < NC; ++i)
#pragma unroll
    for (int j = 0; j < 8; ++j) {
      const unsigned kk = (unsigned)(unsigned short)kv[i][j];
      if ((int)(kk >> 4) == b1) atomicAdd(&chunk[kk & 15], 1);
    }
  __syncthreads();
  if (tid == 0) {
    int run = misc[1];
    int K16 = b1 << 4;
    for (int j = 15; j >= 0; --j) {
      const int c = chunk[j];
      if (run < k && k <= run + c) K16 = (b1 << 4) | j;
      run += c;
    }
    const float v_lo = val_of_key((unsigned short)K16);
    const float v_hi = val_of_key((unsigned short)min(K16 + 1, 65535));
    const float ulp = v_hi - v_lo;
    const float vs = v_hi + delta;          // sure: value >  vs
    const float va = v_lo - ulp - delta;    // amb : value >= va
    int ks = key_of(vs); if (val_of_key((unsigned short)ks) > vs) --ks;   // floor key
    int ka = key_of(va); if (val_of_key((unsigned short)ka) < va) ++ka;   // ceil key
    misc[2] = ks; misc[3] = ka;
  }
  __syncthreads();
  const unsigned ks = (unsigned)misc[2], ka = (unsigned)misc[3];

#pragma unroll
  for (int i = 0; i < NC; ++i)
#pragma unroll
    for (int j = 0; j < 8; ++j) {
      const unsigned kk = (unsigned)(unsigned short)kv[i][j];
      if (kk > ks) {
        const int p = atomicAdd(&misc[4], 1);
        if (p < S_MAX) {
          const int h = (i * 256 + tid) * 8 + j;
          sure_ix[(size_t)b * S_MAX + p] = h;
          sure_val[(size_t)b * S_MAX + p] = val_of_key((unsigned short)kk);
        }
      } else if (kk >= ka) {
        const int p = atomicAdd(&misc[5], 1);
        if (p < A_MAX) amb_ix[(size_t)b * A_MAX + p] = (i * 256 + tid) * 8 + j;
      }
    }
  __syncthreads();
  if (tid == 0) {
    sure_cnt[b] = min(misc[4], S_MAX);
    amb_cnt[b]  = min(misc[5], A_MAX);
  }
}

// ---------------- kernel 3: f64 refine + rank + scatter (R11-verified; row pre-zeroed) ----------------
__global__ __launch_bounds__(256) void refine_scatter(
    const float* __restrict__ X, const float* __restrict__ b_pre,
    const float* __restrict__ W, const float* __restrict__ b_enc,
    const int* __restrict__ sure_ix, const float* __restrict__ sure_val,
    const int* __restrict__ sure_cnt,
    const int* __restrict__ amb_ix, const int* __restrict__ amb_cnt,
    const int* __restrict__ kptr,
    float* __restrict__ hidden, int* __restrict__ tk_idx, float* __restrict__ tk_val, int D)
{
  constexpr int H = H_FIX;
  __shared__ float  xr[D_MAX];
  __shared__ double asv[A_MAX];
  __shared__ int    aix[A_MAX];
  const int tid = threadIdx.x, b = blockIdx.x;
  const int k = min(*kptr, K_MAX);
  const int S = min(min(sure_cnt[b], S_MAX), k);
  const int A = min(amb_cnt[b], A_MAX);
  float* hrow = hidden + (size_t)b * H;

  for (int d = tid; d < D; d += 256) xr[d] = X[(size_t)b * D + d] - b_pre[d];
  for (int c = tid; c < A; c += 256) aix[c] = amb_ix[(size_t)b * A_MAX + c];

  for (int i = tid; i < S; i += 256) {
    const int h = sure_ix[(size_t)b * S_MAX + i];
    const float v = sure_val[(size_t)b * S_MAX + i];
    const float rv = (v > 0.f) ? v : 0.f;
    hrow[h] = rv;
    tk_idx[(size_t)b * K_MAX + i] = h;
    tk_val[(size_t)b * K_MAX + i] = rv;
  }
  __syncthreads();

  const int wid = tid >> 6, lane = tid & 63;
  for (int c = wid; c < A; c += 4) {
    const int h = aix[c];
    const float* wr = W + (size_t)h * D;
    double s0 = 0.0, s1 = 0.0;
    int i = lane;
    for (; i + 64 < D; i += 128) {
      s0 += (double)xr[i] * (double)wr[i];
      s1 += (double)xr[i + 64] * (double)wr[i + 64];
    }
    if (i < D) s0 += (double)xr[i] * (double)wr[i];
    double s = s0 + s1;
    for (int off = 32; off; off >>= 1) s += __shfl_xor(s, off);
    if (lane == 0) asv[c] = s + (double)b_enc[h];
  }
  __syncthreads();

  const int m = k - S;
  for (int c = tid; c < A; c += 256) {
    const double v = asv[c];
    const int h = aix[c];
    int r = 0;
    for (int j = 0; j < A; ++j) {
      const double vj = asv[j];
      r += ((vj > v) || (vj == v && aix[j] < h)) ? 1 : 0;
    }
    if (r < m) {
      const float rv = (v > 0.0) ? (float)v : 0.f;
      hrow[h] = rv;
      tk_idx[(size_t)b * K_MAX + S + r] = h;
      tk_val[(size_t)b * K_MAX + S + r] = rv;
    }
  }
}

// ---------------- fallback: fp32 GEMM ----------------
__global__ __launch_bounds__(256) void enc_gemm_f32(
    const float* __restrict__ X, const float* __restrict__ W,
    const float* __restrict__ b_enc, const float* __restrict__ b_pre,
    float* __restrict__ pre, int D, int H)
{
  __shared__ float As[BKF][BM + 4];
  __shared__ float Bs[BKF][BN + 4];
  const int tid = threadIdx.x;
  const int m0 = blockIdx.y * BM;
  const int n0 = blockIdx.x * BN;
  const int tx = tid & 15, ty = tid >> 4;
  float acc[8][8];
#pragma unroll
  for (int i = 0; i < 8; ++i)
#pragma unroll
    for (int j = 0; j < 8; ++j) acc[i][j] = 0.f;

  for (int kb = 0; kb < D; kb += BKF) {
#pragma unroll
    for (int t = 0; t < 2; ++t) {
      const int f4i = tid + t * 256;
      const int row = f4i >> 2;
      const int kq  = (f4i & 3) << 2;
      float4 xv = *reinterpret_cast<const float4*>(X + (size_t)(m0 + row) * D + kb + kq);
      float4 bp = *reinterpret_cast<const float4*>(b_pre + kb + kq);
      As[kq + 0][row] = xv.x - bp.x; As[kq + 1][row] = xv.y - bp.y;
      As[kq + 2][row] = xv.z - bp.z; As[kq + 3][row] = xv.w - bp.w;
      float4 wv = *reinterpret_cast<const float4*>(W + (size_t)(n0 + row) * D + kb + kq);
      Bs[kq + 0][row] = wv.x; Bs[kq + 1][row] = wv.y;
      Bs[kq + 2][row] = wv.z; Bs[kq + 3][row] = wv.w;
    }
    __syncthreads();
#pragma unroll
    for (int kk = 0; kk < BKF; ++kk) {
      float4 a0 = *reinterpret_cast<const float4*>(&As[kk][ty * 8]);
      float4 a1 = *reinterpret_cast<const float4*>(&As[kk][ty * 8 + 4]);
      float4 b0 = *reinterpret_cast<const float4*>(&Bs[kk][tx * 8]);
      float4 b1 = *reinterpret_cast<const float4*>(&Bs[kk][tx * 8 + 4]);
      float av[8] = {a0.x, a0.y, a0.z, a0.w, a1.x, a1.y, a1.z, a1.w};
      float bv[8] = {b0.x, b0.y, b0.z, b0.w, b1.x, b1.y, b1.z, b1.w};
#pragma unroll
      for (int i = 0; i < 8; ++i)
#pragma unroll
        for (int j = 0; j < 8; ++j) acc[i][j] += av[i] * bv[j];
    }
    __syncthreads();
  }
#pragma unroll
  for (int i = 0; i < 8; ++i) {
    const size_t m = (size_t)(m0 + ty * 8 + i);
#pragma unroll
    for (int j = 0; j < 8; j += 4) {
      const int n = n0 + tx * 8 + j;
      float4 o;
      o.x = acc[i][j + 0] + b_enc[n + 0];
      o.y = acc[i][j + 1] + b_enc[n + 1];
      o.z = acc[i][j + 2] + b_enc[n + 2];
      o.w = acc[i][j + 3] + b_enc[n + 3];
      *reinterpret_cast<float4*>(pre + m * H + n) = o;
    }
  }
}

// ---------------- fallback: bisection top-k (reads f32 pre) ----------------
__global__ __launch_bounds__(256) void topk_refine(
    const float* __restrict__ X, const float* __restrict__ b_pre,
    const float* __restrict__ W, const float* __restrict__ b_enc,
    float* __restrict__ hidden, int* __restrict__ tk_idx, float* __restrict__ tk_val,
    const int* __restrict__ kptr, int D, int H, float margin)
{
  extern __shared__ char smem_raw[];
  double* cand_val = reinterpret_cast<double*>(smem_raw);
  float*  xr       = reinterpret_cast<float*>(cand_val + CAND_MAX);
  int*    cand_idx = reinterpret_cast<int*>(xr + D);
  int*    misc     = cand_idx + CAND_MAX;

  const int tid = threadIdx.x;
  const int b = blockIdx.x;
  const int k = min(*kptr, K_MAX);
  float* hrow = hidden + (size_t)b * H;

  for (int i = tid; i < NBITER + 2; i += 256) misc[i] = 0;
  for (int d = tid; d < D; d += 256) xr[d] = X[(size_t)b * D + d] - b_pre[d];

  float f[64];
#pragma unroll
  for (int i = 0; i < 16; ++i) {
    const int base = i * 1024 + tid * 4;
    float4 v = {-3e38f, -3e38f, -3e38f, -3e38f};
    if (base + 3 < H) v = *reinterpret_cast<const float4*>(hrow + base);
    f[4 * i + 0] = v.x; f[4 * i + 1] = v.y; f[4 * i + 2] = v.z; f[4 * i + 3] = v.w;
  }
  __syncthreads();

  float lo = -1e4f, hi = 1e4f;
  for (int it = 0; it < NBITER; ++it) {
    const float mid = 0.5f * (lo + hi);
    int cnt = 0;
#pragma unroll
    for (int j = 0; j < 64; ++j) cnt += (f[j] >= mid) ? 1 : 0;
    for (int off = 32; off; off >>= 1) cnt += __shfl_xor(cnt, off);
    if ((tid & 63) == 0) atomicAdd(&misc[it], cnt);
    __syncthreads();
    if (misc[it] >= k) lo = mid; else hi = mid;
  }

  const float thresh = lo - margin;
#pragma unroll
  for (int j = 0; j < 64; ++j) {
    if (f[j] >= thresh) {
      const int h = (j >> 2) * 1024 + tid * 4 + (j & 3);
      if (h < H) {
        int pos = atomicAdd(&misc[NBITER], 1);
        if (pos < CAND_MAX) cand_idx[pos] = h;
      }
    }
  }
  __syncthreads();
  const int C = min(misc[NBITER], CAND_MAX);

  const int wid = tid >> 6, lane = tid & 63;
  for (int c = wid; c < C; c += 4) {
    const int h = cand_idx[c];
    const float* wr = W + (size_t)h * D;
    double s = 0.0;
    for (int i = lane; i < D; i += 64) s += (double)xr[i] * (double)wr[i];
    for (int off = 32; off; off >>= 1) s += __shfl_xor(s, off);
    if (lane == 0) cand_val[c] = s + (double)b_enc[h];
  }
  __syncthreads();

  const float4 z4 = {0.f, 0.f, 0.f, 0.f};
  for (int i = tid; i < (H >> 2); i += 256)
    reinterpret_cast<float4*>(hrow)[i] = z4;
  __syncthreads();

  for (int c = tid; c < C; c += 256) {
    const double v = cand_val[c];
    const int h = cand_idx[c];
    int r = 0;
    for (int j = 0; j < C; ++j) {
      const double vj = cand_val[j];
      r += ((vj > v) || (vj == v && cand_idx[j] < h)) ? 1 : 0;
    }
    if (r < k) {
      const float rv = (v > 0.0) ? (float)v : 0.f;
      hrow[h] = rv;
      tk_idx[(size_t)b * K_MAX + r] = h;
      tk_val[(size_t)b * K_MAX + r] = rv;
    }
  }
}

// ---------------- kernel 5: W_dec [D,H] -> bf16 W_decT [H,D] ----------------
__global__ __launch_bounds__(256) void transpose_wdec_bf16(
    const float* __restrict__ Wsrc, unsigned short* __restrict__ WT, int D, int H)
{
  __shared__ float tile[32][33];
  const int c  = threadIdx.x & 31;
  const int r0 = threadIdx.x >> 5;
  const int h0 = blockIdx.x * 32;
  const int d0 = blockIdx.y * 32;
#pragma unroll
  for (int r = r0; r < 32; r += 8) {
    const int d = d0 + r, h = h0 + c;
    if (d < D && h < H) tile[r][c] = Wsrc[(size_t)d * H + h];
  }
  __syncthreads();
#pragma unroll
  for (int r = r0; r < 32; r += 8) {
    const int h = h0 + r, d = d0 + c;
    if (h < H && d < D) WT[(size_t)h * D + d] = f2bf(tile[c][r]);
  }
}

// ---------------- kernel 6: sparse decode + SSE, 2 rows/block, 16B gathers ----------------
__global__ __launch_bounds__(256) void decode_loss2(
    const float* __restrict__ X, const float* __restrict__ b_pre,
    const float* __restrict__ b_dec, const unsigned short* __restrict__ WTb,
    const int* __restrict__ tk_idx, const float* __restrict__ tk_val,
    const int* __restrict__ kptr,
    float* __restrict__ recon, double* __restrict__ row_ssq, int D)
{
  __shared__ int   sidx[2][K_MAX];
  __shared__ float sval[2][K_MAX];
  __shared__ double sd[4];
  const int tid = threadIdx.x;
  const int half = tid >> 7, lt = tid & 127;     // waves 0-1 -> row0, 2-3 -> row1
  const int b = blockIdx.x * 2 + half;
  const int k = min(*kptr, K_MAX);
  if (lt < k) {
    sidx[half][lt] = tk_idx[(size_t)b * K_MAX + lt];
    sval[half][lt] = tk_val[(size_t)b * K_MAX + lt];
  }
  __syncthreads();

  double ssq = 0.0;
  const int D8 = D >> 3;
  for (int dc = lt; dc < D8; dc += 128) {
    const int d = dc * 8;
    float a[8];
#pragma unroll
    for (int q = 0; q < 2; ++q) {
      float4 bd = *reinterpret_cast<const float4*>(b_dec + d + q * 4);
      float4 bp = *reinterpret_cast<const float4*>(b_pre + d + q * 4);
      a[q * 4 + 0] = bd.x + bp.x; a[q * 4 + 1] = bd.y + bp.y;
      a[q * 4 + 2] = bd.z + bp.z; a[q * 4 + 3] = bd.w + bp.w;
    }
#pragma unroll 4
    for (int j = 0; j < k; ++j) {
      const u16x8 w = *reinterpret_cast<const u16x8*>(WTb + (size_t)sidx[half][j] * D + d);
      const float s = sval[half][j];
#pragma unroll
      for (int e = 0; e < 8; ++e) a[e] += s * bf2f((unsigned short)w[e]);
    }
#pragma unroll
    for (int q = 0; q < 2; ++q) {
      float4 o = {a[q * 4 + 0], a[q * 4 + 1], a[q * 4 + 2], a[q * 4 + 3]};
      *reinterpret_cast<float4*>(recon + (size_t)b * D + d + q * 4) = o;
    }
#pragma unroll
    for (int q = 0; q < 2; ++q) {
      float4 xv = *reinterpret_cast<const float4*>(X + (size_t)b * D + d + q * 4);
      const double d0 = (double)a[q * 4 + 0] - (double)xv.x;
      const double d1 = (double)a[q * 4 + 1] - (double)xv.y;
      const double d2 = (double)a[q * 4 + 2] - (double)xv.z;
      const double d3 = (double)a[q * 4 + 3] - (double)xv.w;
      ssq += d0 * d0 + d1 * d1 + d2 * d2 + d3 * d3;
    }
  }
  for (int off = 32; off; off >>= 1) ssq += __shfl_xor(ssq, off);
  if ((tid & 63) == 0) sd[tid >> 6] = ssq;
  __syncthreads();
  if (tid == 0) row_ssq[blockIdx.x * 2 + 0] = sd[0] + sd[1];
  if (tid == 128) row_ssq[blockIdx.x * 2 + 1] = sd[2] + sd[3];
}

// fallback decode (f32 W_dec, strided)
__global__ __launch_bounds__(256) void decode_loss(
    const float* __restrict__ X, const float* __restrict__ b_pre,
    const float* __restrict__ b_dec, const float* __restrict__ Wfull,
    const int* __restrict__ tk_idx, const float* __restrict__ tk_val,
    const int* __restrict__ kptr,
    float* __restrict__ recon, double* __restrict__ row_ssq, int D, int H)
{
  __shared__ int   sidx[K_MAX];
  __shared__ float sval[K_MAX];
  __shared__ double sd[4];
  const int tid = threadIdx.x, b = blockIdx.x;
  const int k = min(*kptr, K_MAX);
  if (tid < k) {
    sidx[tid] = tk_idx[(size_t)b * K_MAX + tid];
    sval[tid] = tk_val[(size_t)b * K_MAX + tid];
  }
  __syncthreads();
  double ssq = 0.0;
  for (int d = tid; d < D; d += 256) {
    float a = b_dec[d] + b_pre[d];
#pragma unroll 4
    for (int j = 0; j < k; ++j) a += sval[j] * Wfull[(size_t)d * H + sidx[j]];
    recon[(size_t)b * D + d] = a;
    const double diff = (double)a - (double)X[(size_t)b * D + d];
    ssq += diff * diff;
  }
  for (int off = 32; off; off >>= 1) ssq += __shfl_xor(ssq, off);
  if ((tid & 63) == 0) sd[tid >> 6] = ssq;
  __syncthreads();
  if (tid == 0) row_ssq[b] = sd[0] + sd[1] + sd[2] + sd[3];
}

// ---------------- kernel 7a: per-chunk partial losses (64 blocks) ----------------
__global__ __launch_bounds__(256) void finalize_part(
    const double* __restrict__ row_ssq, const float* __restrict__ tk_val,
    const int* __restrict__ kptr, double* __restrict__ part_s, int* __restrict__ part_c,
    int Bdim, int rows_per_blk)
{
  __shared__ double sd[4];
  __shared__ int si[4];
  const int tid = threadIdx.x;
  const int k = min(*kptr, K_MAX);
  const int b0 = blockIdx.x * rows_per_blk;
  const int b1 = min(b0 + rows_per_blk, Bdim);
  double s = 0.0;
  for (int i = b0 + tid; i < b1; i += 256) s += row_ssq[i];
  int cnt = 0;
  const int total = (b1 - b0) * k;
  for (int i = tid; i < total; i += 256) {
    const int bb = b0 + i / k, j = i - (i / k) * k;
    cnt += (tk_val[(size_t)bb * K_MAX + j] > 0.f) ? 1 : 0;
  }
  for (int off = 32; off; off >>= 1) { s += __shfl_xor(s, off); cnt += __shfl_xor(cnt, off); }
  if ((tid & 63) == 0) { sd[tid >> 6] = s; si[tid >> 6] = cnt; }
  __syncthreads();
  if (tid == 0) {
    part_s[blockIdx.x] = sd[0] + sd[1] + sd[2] + sd[3];
    part_c[blockIdx.x] = si[0] + si[1] + si[2] + si[3];
  }
}

// ---------------- kernel 7b: final scalar losses ----------------
__global__ __launch_bounds__(64) void finalize_k2(
    const double* __restrict__ part_s, const int* __restrict__ part_c,
    float* __restrict__ scalars, int nparts, int Bdim, int D)
{
  const int tid = threadIdx.x;
  double s = (tid < nparts) ? part_s[tid] : 0.0;
  int cnt = (tid < nparts) ? part_c[tid] : 0;
  for (int off = 32; off; off >>= 1) { s += __shfl_xor(s, off); cnt += __shfl_xor(cnt, off); }
  if (tid == 0) {
    const double rl = s / ((double)Bdim * (double)D);
    scalars[0] = (float)rl;                     // loss
    scalars[1] = (float)rl;                     // reconstruction_loss
    scalars[2] = 0.f;                           // sparsity_loss
    scalars[3] = (float)((double)cnt / Bdim);   // l0
  }
}

extern "C" void kernel_launch(void* const* d_in, const int* in_sizes, int n_in,
                              void* d_out, int out_size, void* d_ws, size_t ws_size,
                              hipStream_t stream)
{
  const float* x     = (const float*)d_in[0];
  const float* W_enc = (const float*)d_in[1];
  const float* b_enc = (const float*)d_in[2];
  const float* W_dec = (const float*)d_in[3];
  const float* b_dec = (const float*)d_in[4];
  const float* b_pre = (const float*)d_in[5];
  const int*   kptr  = (const int*)d_in[6];

  const int D = in_sizes[4];          // 1280
  const int H = in_sizes[2];          // 16384
  const int B = in_sizes[0] / D;      // 8192

  float* recon   = (float*)d_out;
  float* hidden  = recon + (size_t)B * D;       // keys live in each row's 2nd half
  float* scalars = hidden + (size_t)B * H;

  // ---- workspace layout (single running cursor) ----
  size_t off = 0;
  int* tk_idx = (int*)((char*)d_ws + off);        off += (size_t)B * K_MAX * sizeof(int);
  float* tk_val = (float*)((char*)d_ws + off);    off += (size_t)B * K_MAX * sizeof(float);
  off = (off + 7) & ~(size_t)7;
  double* row_ssq = (double*)((char*)d_ws + off); off += (size_t)B * sizeof(double);
  double* part_s = (double*)((char*)d_ws + off);  off += 64 * sizeof(double);
  int* part_c = (int*)((char*)d_ws + off);        off += 64 * sizeof(int);
  off = (off + 7) & ~(size_t)7;

  unsigned short* Xb = (unsigned short*)((char*)d_ws + off);
  off += (size_t)B * D * sizeof(unsigned short);
  unsigned short* Wb = (unsigned short*)((char*)d_ws + off);
  off += (size_t)H * D * sizeof(unsigned short);
  unsigned short* WTb = (unsigned short*)((char*)d_ws + off);
  off += (size_t)D * H * sizeof(unsigned short);

  int* sure_ix = (int*)((char*)d_ws + off);       off += (size_t)B * S_MAX * sizeof(int);
  float* sure_val = (float*)((char*)d_ws + off);  off += (size_t)B * S_MAX * sizeof(float);
  int* sure_cnt = (int*)((char*)d_ws + off);      off += (size_t)B * sizeof(int);
  int* amb_ix = (int*)((char*)d_ws + off);        off += (size_t)B * A_MAX * sizeof(int);
  int* amb_cnt = (int*)((char*)d_ws + off);       off += (size_t)B * sizeof(int);
  const int useFAST = (off <= ws_size) ? 1 : 0;

  const bool fast_ok = (D % 64 == 0) && (D % 8 == 0) && (D <= D_MAX) &&
                       (H == H_FIX) && (B % 256 == 0);

  if (useFAST && fast_ok) {
    const size_t tx4 = (size_t)B * D / 4, tw4 = (size_t)H * D / 4;
    prep_xb<<<2048, 256, 0, stream>>>(x, b_pre, Xb, D, tx4);
    prep_wb<<<2048, 256, 0, stream>>>(W_enc, Wb, tw4);
    dim3 gg(H / 256, B / 256);
    enc_gemm_bf16<<<gg, 512, 0, stream>>>(Xb, Wb, b_enc, hidden, D, H);  // keys + 1st-half zero
    // delta >= 2*(GEMM err ~0.01 + bf16 ulp/2 ~0.008) with slack
    topk_classify_keys<<<B, 256, 0, stream>>>(hidden, sure_ix, sure_val, sure_cnt,
                                              amb_ix, amb_cnt, kptr, 0.05f);
    refine_scatter<<<B, 256, 0, stream>>>(x, b_pre, W_enc, b_enc,
                                          sure_ix, sure_val, sure_cnt,
                                          amb_ix, amb_cnt, kptr,
                                          hidden, tk_idx, tk_val, D);
    transpose_wdec_bf16<<<dim3((H + 31) / 32, (D + 31) / 32), 256, 0, stream>>>(W_dec, WTb, D, H);
    decode_loss2<<<B / 2, 256, 0, stream>>>(x, b_pre, b_dec, WTb,
                                            tk_idx, tk_val, kptr, recon, row_ssq, D);
  } else {
    dim3 gg(H / BN, B / BM);
    enc_gemm_f32<<<gg, 256, 0, stream>>>(x, W_enc, b_enc, b_pre, hidden, D, H);
    const size_t sh = CAND_MAX * sizeof(double) + (size_t)D * sizeof(float)
                    + CAND_MAX * sizeof(int) + (NBITER + 8) * sizeof(int);
    topk_refine<<<B, 256, sh, stream>>>(x, b_pre, W_enc, b_enc, hidden,
                                        tk_idx, tk_val, kptr, D, H, 1e-3f);
    decode_loss<<<B, 256, 0, stream>>>(x, b_pre, b_dec, W_dec,
                                       tk_idx, tk_val, kptr, recon, row_ssq, D, H);
  }

  const int rpb = (B + 63) / 64;
  finalize_part<<<64, 256, 0, stream>>>(row_ssq, tk_val, kptr, part_s, part_c, B, rpb);
  finalize_k2<<<1, 64, 0, stream>>>(part_s, part_c, scalars, 64, B, D);
}

// Round 17
// 990.724 us; speedup vs baseline: 1.0095x; 1.0095x over previous
//
#include <hip/hip_runtime.h>
#include <hip/hip_bf16.h>

constexpr int K_MAX    = 128;   // max supported k (actual k=64 read from device)
constexpr int S_MAX    = 128;   // sure-member cap per row (provably S <= k-1 < 128)
constexpr int A_MAX    = 256;   // ambiguous cap per row
constexpr int CAND_MAX = 512;   // fallback candidate cap
constexpr int BM = 128, BN = 128, BKF = 16;
constexpr int NBITER = 42;      // fallback bisection iterations
constexpr int D_MAX   = 2048;   // fast path requires D <= D_MAX
constexpr int H_FIX   = 16384;  // fast path requires H == H_FIX

typedef __attribute__((ext_vector_type(8))) short bf16x8;
typedef __attribute__((ext_vector_type(8))) unsigned short u16x8;
typedef __attribute__((ext_vector_type(4))) float f32x4;

__device__ inline unsigned short f2bf(float f) {   // round-to-nearest-even
  unsigned u = __float_as_uint(f);
  return (unsigned short)((u + 0x7fff + ((u >> 16) & 1)) >> 16);
}
// monotone 16-bit key: key order == value order (handles negatives)
__device__ inline unsigned short key_of(float f) {
  unsigned short b = f2bf(f);
  return b ^ ((b & 0x8000) ? 0xFFFF : 0x8000);
}
__device__ inline float val_of_key(unsigned short kk) {
  unsigned short b = (kk & 0x8000) ? (unsigned short)(kk ^ 0x8000)
                                   : (unsigned short)(kk ^ 0xFFFF);
  return __uint_as_float(((unsigned)b) << 16);
}
__device__ inline float bf2f(unsigned short b) {
  return __uint_as_float(((unsigned)b) << 16);
}

// conflict-free superrow swizzle (R8-verified: bank conflicts 1.26e8 -> 0)
__device__ inline int lds_slot(int r, int c) {
  return ((r >> 1) << 4) | ((r & 1) << 3) | (c ^ ((r >> 1) & 7));
}

// ---------------- prep: Xb = bf16(x - b_pre), Wb = bf16(W_enc) ----------------
__global__ __launch_bounds__(256) void prep_xb(
    const float* __restrict__ x, const float* __restrict__ b_pre,
    unsigned short* __restrict__ Xb, int D, size_t total4)
{
  for (size_t i = blockIdx.x * 256 + threadIdx.x; i < total4; i += (size_t)gridDim.x * 256) {
    const size_t e = i * 4;
    const int d = (int)(e % D);
    float4 xv = *reinterpret_cast<const float4*>(x + e);
    float4 bp = *reinterpret_cast<const float4*>(b_pre + d);
    ushort4 o;
    o.x = f2bf(xv.x - bp.x); o.y = f2bf(xv.y - bp.y);
    o.z = f2bf(xv.z - bp.z); o.w = f2bf(xv.w - bp.w);
    *reinterpret_cast<ushort4*>(Xb + e) = o;
  }
}

__global__ __launch_bounds__(256) void prep_wb(
    const float* __restrict__ W, unsigned short* __restrict__ Wb, size_t total4)
{
  for (size_t i = blockIdx.x * 256 + threadIdx.x; i < total4; i += (size_t)gridDim.x * 256) {
    const size_t e = i * 4;
    float4 wv = *reinterpret_cast<const float4*>(W + e);
    ushort4 o;
    o.x = f2bf(wv.x); o.y = f2bf(wv.y); o.z = f2bf(wv.z); o.w = f2bf(wv.w);
    *reinterpret_cast<ushort4*>(Wb + e) = o;
  }
}

// ---------------- kernel 1: encoder GEMM 256x256, 8 waves, 4-phase counted-vmcnt ----------------
// (R11/R13-verified K-loop: MfmaUtil ~44%.) Per-wave 64(M)x128(N). K-tile=64.
// Keys go to each hidden row's SECOND half; this block's share of the FIRST half
// is zero-filled by stores issued at kernel START (R17: drain under the K-loop;
// R16 epilogue placement exposed them at the tail, +50us).
__global__ __launch_bounds__(512, 2) void enc_gemm_bf16(
    const unsigned short* __restrict__ Xb, const unsigned short* __restrict__ Wb,
    const float* __restrict__ b_enc, float* __restrict__ pre, int D, int H)
{
  __shared__ unsigned short As[2][2048 * 8];
  __shared__ unsigned short Bs[2][2048 * 8];
  const int tid  = threadIdx.x;
  const int wave = tid >> 6, lane = tid & 63;
  const int m0 = blockIdx.y * 256, n0 = blockIdx.x * 256;
  const int wm = (wave >> 1) * 64;
  const int wn = (wave & 1) * 128;
  const int l16 = lane & 15, lhi = lane >> 4;

  f32x4 acc[4][8];
#pragma unroll
  for (int i = 0; i < 4; ++i)
#pragma unroll
    for (int j = 0; j < 8; ++j) acc[i][j] = (f32x4){0.f, 0.f, 0.f, 0.f};

  const int NT = D / 64;

  // zero this block's share of the hidden first half FIRST (fire-and-forget;
  // drains under the compute-bound K-loop). vmcnt waits below become at most
  // more conservative in tile 0 (stores sit ahead of loads in the queue).
  {
    const int zc0 = n0 >> 1;
    const f32x4 z4 = (f32x4){0.f, 0.f, 0.f, 0.f};
#pragma unroll
    for (int i = 0; i < 16; ++i) {
      const int idx = i * 512 + tid;       // 0..8191 = 256 rows x 32 chunks
      const int row = idx >> 5;
      const int c4  = idx & 31;
      *reinterpret_cast<f32x4*>(pre + (size_t)(m0 + row) * H + zc0 + c4 * 4) = z4;
    }
  }

  auto stageA = [&](int buf, int h, int kb) {
#pragma unroll
    for (int i = 0; i < 2; ++i) {
      const int idx = i * 512 + wave * 64 + lane;
      const int sr = idx >> 4, u = idx & 15;
      const int r  = (sr << 1) | (u >> 3);
      const int ch = (u & 7) ^ (sr & 7);
      __builtin_amdgcn_global_load_lds(
          (const __attribute__((address_space(1))) unsigned int*)
              (Xb + (size_t)(m0 + h * 128 + r) * D + kb + ch * 8),
          (__attribute__((address_space(3))) unsigned int*)
              (&As[buf][(size_t)(h * 1024 + idx) * 8]), 16, 0, 0);
    }
  };
  auto stageBq = [&](int buf, int q, int kb) {
    const int s  = (q & 1) * 512 + wave * 64 + lane;
    const int sr = s >> 4, u = s & 15;
    const int r  = (sr << 1) | (u >> 3);
    const int ch = (u & 7) ^ (sr & 7);
    __builtin_amdgcn_global_load_lds(
        (const __attribute__((address_space(1))) unsigned int*)
            (Wb + (size_t)(n0 + (q >> 1) * 128 + r) * D + kb + ch * 8),
        (__attribute__((address_space(3))) unsigned int*)
            (&Bs[buf][(size_t)((q >> 1) * 1024 + s) * 8]), 16, 0, 0);
  };
  auto readA = [&](int buf, int mi, int kk) -> bf16x8 {
    const int gr = wm + mi * 16 + l16;
    return *reinterpret_cast<const bf16x8*>(
        &As[buf][(size_t)((gr >> 7) * 1024 + lds_slot(gr & 127, kk * 4 + lhi)) * 8]);
  };
  auto readB = [&](int buf, int ni, int kk) -> bf16x8 {
    const int gr = wn + ni * 16 + l16;
    return *reinterpret_cast<const bf16x8*>(
        &Bs[buf][(size_t)((gr >> 7) * 1024 + lds_slot(gr & 127, kk * 4 + lhi)) * 8]);
  };

  stageA(0, 0, 0); stageA(0, 1, 0);
  stageBq(0, 0, 0); stageBq(0, 2, 0);
  stageBq(0, 1, 0); stageBq(0, 3, 0);

  int cur = 0;
  for (int t = 0; t < NT; ++t) {
    const int nxt = cur ^ 1;
    const int kb1 = (t + 1) * 64;
    const bool more = (t + 1 < NT);

    bf16x8 af[4][2], bf[2][2];

    asm volatile("s_waitcnt vmcnt(2)" ::: "memory");
    __builtin_amdgcn_s_barrier();
#pragma unroll
    for (int mi = 0; mi < 4; ++mi)
#pragma unroll
      for (int kk = 0; kk < 2; ++kk) af[mi][kk] = readA(cur, mi, kk);
#pragma unroll
    for (int j = 0; j < 2; ++j)
#pragma unroll
      for (int kk = 0; kk < 2; ++kk) bf[j][kk] = readB(cur, j, kk);
    if (more) stageA(nxt, 0, kb1);
    __builtin_amdgcn_s_setprio(1);
#pragma unroll
    for (int mi = 0; mi < 4; ++mi)
#pragma unroll
      for (int j = 0; j < 2; ++j)
#pragma unroll
        for (int kk = 0; kk < 2; ++kk)
          acc[mi][j] = __builtin_amdgcn_mfma_f32_16x16x32_bf16(af[mi][kk], bf[j][kk], acc[mi][j], 0, 0, 0);
    __builtin_amdgcn_s_setprio(0);

#pragma unroll
    for (int j = 0; j < 2; ++j)
#pragma unroll
      for (int kk = 0; kk < 2; ++kk) bf[j][kk] = readB(cur, 2 + j, kk);
    if (more) stageA(nxt, 1, kb1);
    __builtin_amdgcn_s_setprio(1);
#pragma unroll
    for (int mi = 0; mi < 4; ++mi)
#pragma unroll
      for (int j = 0; j < 2; ++j)
#pragma unroll
        for (int kk = 0; kk < 2; ++kk)
          acc[mi][2 + j] = __builtin_amdgcn_mfma_f32_16x16x32_bf16(af[mi][kk], bf[j][kk], acc[mi][2 + j], 0, 0, 0);
    __builtin_amdgcn_s_setprio(0);

    if (more) { asm volatile("s_waitcnt vmcnt(4)" ::: "memory"); }
    else      { asm volatile("s_waitcnt vmcnt(0)" ::: "memory"); }
    __builtin_amdgcn_s_barrier();
#pragma unroll
    for (int j = 0; j < 2; ++j)
#pragma unroll
      for (int kk = 0; kk < 2; ++kk) bf[j][kk] = readB(cur, 4 + j, kk);
    if (more) { stageBq(nxt, 0, kb1); stageBq(nxt, 2, kb1); }
    __builtin_amdgcn_s_setprio(1);
#pragma unroll
    for (int mi = 0; mi < 4; ++mi)
#pragma unroll
      for (int j = 0; j < 2; ++j)
#pragma unroll
        for (int kk = 0; kk < 2; ++kk)
          acc[mi][4 + j] = __builtin_amdgcn_mfma_f32_16x16x32_bf16(af[mi][kk], bf[j][kk], acc[mi][4 + j], 0, 0, 0);
    __builtin_amdgcn_s_setprio(0);

#pragma unroll
    for (int j = 0; j < 2; ++j)
#pragma unroll
      for (int kk = 0; kk < 2; ++kk) bf[j][kk] = readB(cur, 6 + j, kk);
    if (more) { stageBq(nxt, 1, kb1); stageBq(nxt, 3, kb1); }
    __builtin_amdgcn_s_setprio(1);
#pragma unroll
    for (int mi = 0; mi < 4; ++mi)
#pragma unroll
      for (int j = 0; j < 2; ++j)
#pragma unroll
        for (int kk = 0; kk < 2; ++kk)
          acc[mi][6 + j] = __builtin_amdgcn_mfma_f32_16x16x32_bf16(af[mi][kk], bf[j][kk], acc[mi][6 + j], 0, 0, 0);
    __builtin_amdgcn_s_setprio(0);

    cur = nxt;
  }

  // epilogue: write monotone u16 keys into each row's SECOND half
#pragma unroll
  for (int ni = 0; ni < 8; ++ni) {
    const int n = n0 + wn + ni * 16 + l16;
    const float be = b_enc[n];
#pragma unroll
    for (int mi = 0; mi < 4; ++mi) {
      const int mbase = m0 + wm + mi * 16 + lhi * 4;
#pragma unroll
      for (int r = 0; r < 4; ++r) {
        unsigned short* prow = (unsigned short*)(pre + (size_t)(mbase + r) * H + (H >> 1));
        prow[n] = key_of(acc[mi][ni][r] + be);
      }
    }
  }
}

// ---------------- kernel 2: key classify; zeroes only its row's SECOND half ----------------
__global__ __launch_bounds__(256) void topk_classify_keys(
    float* __restrict__ hidden,
    int* __restrict__ sure_ix, float* __restrict__ sure_val, int* __restrict__ sure_cnt,
    int* __restrict__ amb_ix, int* __restrict__ amb_cnt,
    const int* __restrict__ kptr, float delta)
{
  constexpr int H = H_FIX, NC = H_FIX / (256 * 8);
  __shared__ int hist[4096];
  __shared__ int chunk[256];
  __shared__ int misc[8];

  const int tid = threadIdx.x, b = blockIdx.x;
  const int k = min(*kptr, K_MAX);
  float* hrow = hidden + (size_t)b * H;
  const unsigned short* krow = (const unsigned short*)(hrow + (H >> 1));

  if (tid < 8) misc[tid] = 0;
  for (int i = tid; i < 4096; i += 256) hist[i] = 0;

  u16x8 kv[NC];
#pragma unroll
  for (int i = 0; i < NC; ++i)
    kv[i] = *reinterpret_cast<const u16x8*>(krow + ((size_t)i * 256 + tid) * 8);
  __syncthreads();   // keys in registers before their region is overwritten

  // zero the second half of the row (first half was zeroed by the GEMM)
  const float4 z4 = {0.f, 0.f, 0.f, 0.f};
  float4* z2 = reinterpret_cast<float4*>(hrow + (H >> 1));
  for (int i = tid; i < (H >> 3); i += 256) z2[i] = z4;

#pragma unroll
  for (int i = 0; i < NC; ++i)
#pragma unroll
    for (int j = 0; j < 8; ++j)
      atomicAdd(&hist[((unsigned)(unsigned short)kv[i][j]) >> 4], 1);
  __syncthreads();

  int csum = 0;
#pragma unroll
  for (int j = 0; j < 16; ++j) csum += hist[tid * 16 + j];
  chunk[tid] = csum;
  __syncthreads();
  int gt = 0;
  for (int j = tid + 1; j < 256; ++j) gt += chunk[j];
  {
    int run = gt;
#pragma unroll
    for (int j = 15; j >= 0; --j) {
      const int hc = hist[tid * 16 + j];
      if (run < k && k <= run + hc) { misc[0] = tid * 16 + j; misc[1] = run; }
      run += hc;
    }
  }
  __syncthreads();
  const int b1 = misc[0];
  if (tid < 16) chunk[tid] = 0;
  __syncthreads();
#pragma unroll
  for (int i = 0; i < NC; ++i)
#pragma unroll
    for (int j = 0; j < 8; ++j) {
      const unsigned kk = (unsigned)(unsigned short)kv[i][j];
      if ((int)(kk >> 4) == b1) atomicAdd(&chunk[kk & 15], 1);
    }
  __syncthreads();
  if (tid == 0) {
    int run = misc[1];
    int K16 = b1 << 4;
    for (int j = 15; j >= 0; --j) {
      const int c = chunk[j];
      if (run < k && k <= run + c) K16 = (b1 << 4) | j;
      run += c;
    }
    const float v_lo = val_of_key((unsigned short)K16);
    const float v_hi = val_of_key((unsigned short)min(K16 + 1, 65535));
    const float ulp = v_hi - v_lo;
    const float vs = v_hi + delta;          // sure: value >  vs
    const float va = v_lo - ulp - delta;    // amb : value >= va
    int ks = key_of(vs); if (val_of_key((unsigned short)ks) > vs) --ks;   // floor key
    int ka = key_of(va); if (val_of_key((unsigned short)ka) < va) ++ka;   // ceil key
    misc[2] = ks; misc[3] = ka;
  }
  __syncthreads();
  const unsigned ks = (unsigned)misc[2], ka = (unsigned)misc[3];

#pragma unroll
  for (int i = 0; i < NC; ++i)
#pragma unroll
    for (int j = 0; j < 8; ++j) {
      const unsigned kk = (unsigned)(unsigned short)kv[i][j];
      if (kk > ks) {
        const int p = atomicAdd(&misc[4], 1);
        if (p < S_MAX) {
          const int h = (i * 256 + tid) * 8 + j;
          sure_ix[(size_t)b * S_MAX + p] = h;
          sure_val[(size_t)b * S_MAX + p] = val_of_key((unsigned short)kk);
        }
      } else if (kk >= ka) {
        const int p = atomicAdd(&misc[5], 1);
        if (p < A_MAX) amb_ix[(size_t)b * A_MAX + p] = (i * 256 + tid) * 8 + j;
      }
    }
  __syncthreads();
  if (tid == 0) {
    sure_cnt[b] = min(misc[4], S_MAX);
    amb_cnt[b]  = min(misc[5], A_MAX);
  }
}

// ---------------- kernel 3: f64 refine + rank + scatter (R11-verified; row pre-zeroed) ----------------
__global__ __launch_bounds__(256) void refine_scatter(
    const float* __restrict__ X, const float* __restrict__ b_pre,
    const float* __restrict__ W, const float* __restrict__ b_enc,
    const int* __restrict__ sure_ix, const float* __restrict__ sure_val,
    const int* __restrict__ sure_cnt,
    const int* __restrict__ amb_ix, const int* __restrict__ amb_cnt,
    const int* __restrict__ kptr,
    float* __restrict__ hidden, int* __restrict__ tk_idx, float* __restrict__ tk_val, int D)
{
  constexpr int H = H_FIX;
  __shared__ float  xr[D_MAX];
  __shared__ double asv[A_MAX];
  __shared__ int    aix[A_MAX];
  const int tid = threadIdx.x, b = blockIdx.x;
  const int k = min(*kptr, K_MAX);
  const int S = min(min(sure_cnt[b], S_MAX), k);
  const int A = min(amb_cnt[b], A_MAX);
  float* hrow = hidden + (size_t)b * H;

  for (int d = tid; d < D; d += 256) xr[d] = X[(size_t)b * D + d] - b_pre[d];
  for (int c = tid; c < A; c += 256) aix[c] = amb_ix[(size_t)b * A_MAX + c];

  for (int i = tid; i < S; i += 256) {
    const int h = sure_ix[(size_t)b * S_MAX + i];
    const float v = sure_val[(size_t)b * S_MAX + i];
    const float rv = (v > 0.f) ? v : 0.f;
    hrow[h] = rv;
    tk_idx[(size_t)b * K_MAX + i] = h;
    tk_val[(size_t)b * K_MAX + i] = rv;
  }
  __syncthreads();

  const int wid = tid >> 6, lane = tid & 63;
  for (int c = wid; c < A; c += 4) {
    const int h = aix[c];
    const float* wr = W + (size_t)h * D;
    double s0 = 0.0, s1 = 0.0;
    int i = lane;
    for (; i + 64 < D; i += 128) {
      s0 += (double)xr[i] * (double)wr[i];
      s1 += (double)xr[i + 64] * (double)wr[i + 64];
    }
    if (i < D) s0 += (double)xr[i] * (double)wr[i];
    double s = s0 + s1;
    for (int off = 32; off; off >>= 1) s += __shfl_xor(s, off);
    if (lane == 0) asv[c] = s + (double)b_enc[h];
  }
  __syncthreads();

  const int m = k - S;
  for (int c = tid; c < A; c += 256) {
    const double v = asv[c];
    const int h = aix[c];
    int r = 0;
    for (int j = 0; j < A; ++j) {
      const double vj = asv[j];
      r += ((vj > v) || (vj == v && aix[j] < h)) ? 1 : 0;
    }
    if (r < m) {
      const float rv = (v > 0.0) ? (float)v : 0.f;
      hrow[h] = rv;
      tk_idx[(size_t)b * K_MAX + S + r] = h;
      tk_val[(size_t)b * K_MAX + S + r] = rv;
    }
  }
}

// ---------------- fallback: fp32 GEMM ----------------
__global__ __launch_bounds__(256) void enc_gemm_f32(
    const float* __restrict__ X, const float* __restrict__ W,
    const float* __restrict__ b_enc, const float* __restrict__ b_pre,
    float* __restrict__ pre, int D, int H)
{
  __shared__ float As[BKF][BM + 4];
  __shared__ float Bs[BKF][BN + 4];
  const int tid = threadIdx.x;
  const int m0 = blockIdx.y * BM;
  const int n0 = blockIdx.x * BN;
  const int tx = tid & 15, ty = tid >> 4;
  float acc[8][8];
#pragma unroll
  for (int i = 0; i < 8; ++i)
#pragma unroll
    for (int j = 0; j < 8; ++j) acc[i][j] = 0.f;

  for (int kb = 0; kb < D; kb += BKF) {
#pragma unroll
    for (int t = 0; t < 2; ++t) {
      const int f4i = tid + t * 256;
      const int row = f4i >> 2;
      const int kq  = (f4i & 3) << 2;
      float4 xv = *reinterpret_cast<const float4*>(X + (size_t)(m0 + row) * D + kb + kq);
      float4 bp = *reinterpret_cast<const float4*>(b_pre + kb + kq);
      As[kq + 0][row] = xv.x - bp.x; As[kq + 1][row] = xv.y - bp.y;
      As[kq + 2][row] = xv.z - bp.z; As[kq + 3][row] = xv.w - bp.w;
      float4 wv = *reinterpret_cast<const float4*>(W + (size_t)(n0 + row) * D + kb + kq);
      Bs[kq + 0][row] = wv.x; Bs[kq + 1][row] = wv.y;
      Bs[kq + 2][row] = wv.z; Bs[kq + 3][row] = wv.w;
    }
    __syncthreads();
#pragma unroll
    for (int kk = 0; kk < BKF; ++kk) {
      float4 a0 = *reinterpret_cast<const float4*>(&As[kk][ty * 8]);
      float4 a1 = *reinterpret_cast<const float4*>(&As[kk][ty * 8 + 4]);
      float4 b0 = *reinterpret_cast<const float4*>(&Bs[kk][tx * 8]);
      float4 b1 = *reinterpret_cast<const float4*>(&Bs[kk][tx * 8 + 4]);
      float av[8] = {a0.x, a0.y, a0.z, a0.w, a1.x, a1.y, a1.z, a1.w};
      float bv[8] = {b0.x, b0.y, b0.z, b0.w, b1.x, b1.y, b1.z, b1.w};
#pragma unroll
      for (int i = 0; i < 8; ++i)
#pragma unroll
        for (int j = 0; j < 8; ++j) acc[i][j] += av[i] * bv[j];
    }
    __syncthreads();
  }
#pragma unroll
  for (int i = 0; i < 8; ++i) {
    const size_t m = (size_t)(m0 + ty * 8 + i);
#pragma unroll
    for (int j = 0; j < 8; j += 4) {
      const int n = n0 + tx * 8 + j;
      float4 o;
      o.x = acc[i][j + 0] + b_enc[n + 0];
      o.y = acc[i][j + 1] + b_enc[n + 1];
      o.z = acc[i][j + 2] + b_enc[n + 2];
      o.w = acc[i][j + 3] + b_enc[n + 3];
      *reinterpret_cast<float4*>(pre + m * H + n) = o;
    }
  }
}

// ---------------- fallback: bisection top-k (reads f32 pre) ----------------
__global__ __launch_bounds__(256) void topk_refine(
    const float* __restrict__ X, const float* __restrict__ b_pre,
    const float* __restrict__ W, const float* __restrict__ b_enc,
    float* __restrict__ hidden, int* __restrict__ tk_idx, float* __restrict__ tk_val,
    const int* __restrict__ kptr, int D, int H, float margin)
{
  extern __shared__ char smem_raw[];
  double* cand_val = reinterpret_cast<double*>(smem_raw);
  float*  xr       = reinterpret_cast<float*>(cand_val + CAND_MAX);
  int*    cand_idx = reinterpret_cast<int*>(xr + D);
  int*    misc     = cand_idx + CAND_MAX;

  const int tid = threadIdx.x;
  const int b = blockIdx.x;
  const int k = min(*kptr, K_MAX);
  float* hrow = hidden + (size_t)b * H;

  for (int i = tid; i < NBITER + 2; i += 256) misc[i] = 0;
  for (int d = tid; d < D; d += 256) xr[d] = X[(size_t)b * D + d] - b_pre[d];

  float f[64];
#pragma unroll
  for (int i = 0; i < 16; ++i) {
    const int base = i * 1024 + tid * 4;
    float4 v = {-3e38f, -3e38f, -3e38f, -3e38f};
    if (base + 3 < H) v = *reinterpret_cast<const float4*>(hrow + base);
    f[4 * i + 0] = v.x; f[4 * i + 1] = v.y; f[4 * i + 2] = v.z; f[4 * i + 3] = v.w;
  }
  __syncthreads();

  float lo = -1e4f, hi = 1e4f;
  for (int it = 0; it < NBITER; ++it) {
    const float mid = 0.5f * (lo + hi);
    int cnt = 0;
#pragma unroll
    for (int j = 0; j < 64; ++j) cnt += (f[j] >= mid) ? 1 : 0;
    for (int off = 32; off; off >>= 1) cnt += __shfl_xor(cnt, off);
    if ((tid & 63) == 0) atomicAdd(&misc[it], cnt);
    __syncthreads();
    if (misc[it] >= k) lo = mid; else hi = mid;
  }

  const float thresh = lo - margin;
#pragma unroll
  for (int j = 0; j < 64; ++j) {
    if (f[j] >= thresh) {
      const int h = (j >> 2) * 1024 + tid * 4 + (j & 3);
      if (h < H) {
        int pos = atomicAdd(&misc[NBITER], 1);
        if (pos < CAND_MAX) cand_idx[pos] = h;
      }
    }
  }
  __syncthreads();
  const int C = min(misc[NBITER], CAND_MAX);

  const int wid = tid >> 6, lane = tid & 63;
  for (int c = wid; c < C; c += 4) {
    const int h = cand_idx[c];
    const float* wr = W + (size_t)h * D;
    double s = 0.0;
    for (int i = lane; i < D; i += 64) s += (double)xr[i] * (double)wr[i];
    for (int off = 32; off; off >>= 1) s += __shfl_xor(s, off);
    if (lane == 0) cand_val[c] = s + (double)b_enc[h];
  }
  __syncthreads();

  const float4 z4 = {0.f, 0.f, 0.f, 0.f};
  for (int i = tid; i < (H >> 2); i += 256)
    reinterpret_cast<float4*>(hrow)[i] = z4;
  __syncthreads();

  for (int c = tid; c < C; c += 256) {
    const double v = cand_val[c];
    const int h = cand_idx[c];
    int r = 0;
    for (int j = 0; j < C; ++j) {
      const double vj = cand_val[j];
      r += ((vj > v) || (vj == v && cand_idx[j] < h)) ? 1 : 0;
    }
    if (r < k) {
      const float rv = (v > 0.0) ? (float)v : 0.f;
      hrow[h] = rv;
      tk_idx[(size_t)b * K_MAX + r] = h;
      tk_val[(size_t)b * K_MAX + r] = rv;
    }
  }
}

// ---------------- kernel 5: W_dec [D,H] -> bf16 W_decT [H,D] ----------------
__global__ __launch_bounds__(256) void transpose_wdec_bf16(
    const float* __restrict__ Wsrc, unsigned short* __restrict__ WT, int D, int H)
{
  __shared__ float tile[32][33];
  const int c  = threadIdx.x & 31;
  const int r0 = threadIdx.x >> 5;
  const int h0 = blockIdx.x * 32;
  const int d0 = blockIdx.y * 32;
#pragma unroll
  for (int r = r0; r < 32; r += 8) {
    const int d = d0 + r, h = h0 + c;
    if (d < D && h < H) tile[r][c] = Wsrc[(size_t)d * H + h];
  }
  __syncthreads();
#pragma unroll
  for (int r = r0; r < 32; r += 8) {
    const int h = h0 + r, d = d0 + c;
    if (h < H && d < D) WT[(size_t)h * D + d] = f2bf(tile[c][r]);
  }
}

// ---------------- kernel 6: sparse decode + SSE, 2 rows/block, 16B gathers ----------------
__global__ __launch_bounds__(256) void decode_loss2(
    const float* __restrict__ X, const float* __restrict__ b_pre,
    const float* __restrict__ b_dec, const unsigned short* __restrict__ WTb,
    const int* __restrict__ tk_idx, const float* __restrict__ tk_val,
    const int* __restrict__ kptr,
    float* __restrict__ recon, double* __restrict__ row_ssq, int D)
{
  __shared__ int   sidx[2][K_MAX];
  __shared__ float sval[2][K_MAX];
  __shared__ double sd[4];
  const int tid = threadIdx.x;
  const int half = tid >> 7, lt = tid & 127;     // waves 0-1 -> row0, 2-3 -> row1
  const int b = blockIdx.x * 2 + half;
  const int k = min(*kptr, K_MAX);
  if (lt < k) {
    sidx[half][lt] = tk_idx[(size_t)b * K_MAX + lt];
    sval[half][lt] = tk_val[(size_t)b * K_MAX + lt];
  }
  __syncthreads();

  double ssq = 0.0;
  const int D8 = D >> 3;
  for (int dc = lt; dc < D8; dc += 128) {
    const int d = dc * 8;
    float a[8];
#pragma unroll
    for (int q = 0; q < 2; ++q) {
      float4 bd = *reinterpret_cast<const float4*>(b_dec + d + q * 4);
      float4 bp = *reinterpret_cast<const float4*>(b_pre + d + q * 4);
      a[q * 4 + 0] = bd.x + bp.x; a[q * 4 + 1] = bd.y + bp.y;
      a[q * 4 + 2] = bd.z + bp.z; a[q * 4 + 3] = bd.w + bp.w;
    }
#pragma unroll 4
    for (int j = 0; j < k; ++j) {
      const u16x8 w = *reinterpret_cast<const u16x8*>(WTb + (size_t)sidx[half][j] * D + d);
      const float s = sval[half][j];
#pragma unroll
      for (int e = 0; e < 8; ++e) a[e] += s * bf2f((unsigned short)w[e]);
    }
#pragma unroll
    for (int q = 0; q < 2; ++q) {
      float4 o = {a[q * 4 + 0], a[q * 4 + 1], a[q * 4 + 2], a[q * 4 + 3]};
      *reinterpret_cast<float4*>(recon + (size_t)b * D + d + q * 4) = o;
    }
#pragma unroll
    for (int q = 0; q < 2; ++q) {
      float4 xv = *reinterpret_cast<const float4*>(X + (size_t)b * D + d + q * 4);
      const double d0 = (double)a[q * 4 + 0] - (double)xv.x;
      const double d1 = (double)a[q * 4 + 1] - (double)xv.y;
      const double d2 = (double)a[q * 4 + 2] - (double)xv.z;
      const double d3 = (double)a[q * 4 + 3] - (double)xv.w;
      ssq += d0 * d0 + d1 * d1 + d2 * d2 + d3 * d3;
    }
  }
  for (int off = 32; off; off >>= 1) ssq += __shfl_xor(ssq, off);
  if ((tid & 63) == 0) sd[tid >> 6] = ssq;
  __syncthreads();
  if (tid == 0) row_ssq[blockIdx.x * 2 + 0] = sd[0] + sd[1];
  if (tid == 128) row_ssq[blockIdx.x * 2 + 1] = sd[2] + sd[3];
}

// fallback decode (f32 W_dec, strided)
__global__ __launch_bounds__(256) void decode_loss(
    const float* __restrict__ X, const float* __restrict__ b_pre,
    const float* __restrict__ b_dec, const float* __restrict__ Wfull,
    const int* __restrict__ tk_idx, const float* __restrict__ tk_val,
    const int* __restrict__ kptr,
    float* __restrict__ recon, double* __restrict__ row_ssq, int D, int H)
{
  __shared__ int   sidx[K_MAX];
  __shared__ float sval[K_MAX];
  __shared__ double sd[4];
  const int tid = threadIdx.x, b = blockIdx.x;
  const int k = min(*kptr, K_MAX);
  if (tid < k) {
    sidx[tid] = tk_idx[(size_t)b * K_MAX + tid];
    sval[tid] = tk_val[(size_t)b * K_MAX + tid];
  }
  __syncthreads();
  double ssq = 0.0;
  for (int d = tid; d < D; d += 256) {
    float a = b_dec[d] + b_pre[d];
#pragma unroll 4
    for (int j = 0; j < k; ++j) a += sval[j] * Wfull[(size_t)d * H + sidx[j]];
    recon[(size_t)b * D + d] = a;
    const double diff = (double)a - (double)X[(size_t)b * D + d];
    ssq += diff * diff;
  }
  for (int off = 32; off; off >>= 1) ssq += __shfl_xor(ssq, off);
  if ((tid & 63) == 0) sd[tid >> 6] = ssq;
  __syncthreads();
  if (tid == 0) row_ssq[b] = sd[0] + sd[1] + sd[2] + sd[3];
}

// ---------------- kernel 7a: per-chunk partial losses (64 blocks) ----------------
__global__ __launch_bounds__(256) void finalize_part(
    const double* __restrict__ row_ssq, const float* __restrict__ tk_val,
    const int* __restrict__ kptr, double* __restrict__ part_s, int* __restrict__ part_c,
    int Bdim, int rows_per_blk)
{
  __shared__ double sd[4];
  __shared__ int si[4];
  const int tid = threadIdx.x;
  const int k = min(*kptr, K_MAX);
  const int b0 = blockIdx.x * rows_per_blk;
  const int b1 = min(b0 + rows_per_blk, Bdim);
  double s = 0.0;
  for (int i = b0 + tid; i < b1; i += 256) s += row_ssq[i];
  int cnt = 0;
  const int total = (b1 - b0) * k;
  for (int i = tid; i < total; i += 256) {
    const int bb = b0 + i / k, j = i - (i / k) * k;
    cnt += (tk_val[(size_t)bb * K_MAX + j] > 0.f) ? 1 : 0;
  }
  for (int off = 32; off; off >>= 1) { s += __shfl_xor(s, off); cnt += __shfl_xor(cnt, off); }
  if ((tid & 63) == 0) { sd[tid >> 6] = s; si[tid >> 6] = cnt; }
  __syncthreads();
  if (tid == 0) {
    part_s[blockIdx.x] = sd[0] + sd[1] + sd[2] + sd[3];
    part_c[blockIdx.x] = si[0] + si[1] + si[2] + si[3];
  }
}

// ---------------- kernel 7b: final scalar losses ----------------
__global__ __launch_bounds__(64) void finalize_k2(
    const double* __restrict__ part_s, const int* __restrict__ part_c,
    float* __restrict__ scalars, int nparts, int Bdim, int D)
{
  const int tid = threadIdx.x;
  double s = (tid < nparts) ? part_s[tid] : 0.0;
  int cnt = (tid < nparts) ? part_c[tid] : 0;
  for (int off = 32; off; off >>= 1) { s += __shfl_xor(s, off); cnt += __shfl_xor(cnt, off); }
  if (tid == 0) {
    const double rl = s / ((double)Bdim * (double)D);
    scalars[0] = (float)rl;                     // loss
    scalars[1] = (float)rl;                     // reconstruction_loss
    scalars[2] = 0.f;                           // sparsity_loss
    scalars[3] = (float)((double)cnt / Bdim);   // l0
  }
}

extern "C" void kernel_launch(void* const* d_in, const int* in_sizes, int n_in,
                              void* d_out, int out_size, void* d_ws, size_t ws_size,
                              hipStream_t stream)
{
  const float* x     = (const float*)d_in[0];
  const float* W_enc = (const float*)d_in[1];
  const float* b_enc = (const float*)d_in[2];
  const float* W_dec = (const float*)d_in[3];
  const float* b_dec = (const float*)d_in[4];
  const float* b_pre = (const float*)d_in[5];
  const int*   kptr  = (const int*)d_in[6];

  const int D = in_sizes[4];          // 1280
  const int H = in_sizes[2];          // 16384
  const int B = in_sizes[0] / D;      // 8192

  float* recon   = (float*)d_out;
  float* hidden  = recon + (size_t)B * D;       // keys live in each row's 2nd half
  float* scalars = hidden + (size_t)B * H;

  // ---- workspace layout (single running cursor) ----
  size_t off = 0;
  int* tk_idx = (int*)((char*)d_ws + off);        off += (size_t)B * K_MAX * sizeof(int);
  float* tk_val = (float*)((char*)d_ws + off);    off += (size_t)B * K_MAX * sizeof(float);
  off = (off + 7) & ~(size_t)7;
  double* row_ssq = (double*)((char*)d_ws + off); off += (size_t)B * sizeof(double);
  double* part_s = (double*)((char*)d_ws + off);  off += 64 * sizeof(double);
  int* part_c = (int*)((char*)d_ws + off);        off += 64 * sizeof(int);
  off = (off + 7) & ~(size_t)7;

  unsigned short* Xb = (unsigned short*)((char*)d_ws + off);
  off += (size_t)B * D * sizeof(unsigned short);
  unsigned short* Wb = (unsigned short*)((char*)d_ws + off);
  off += (size_t)H * D * sizeof(unsigned short);
  unsigned short* WTb = (unsigned short*)((char*)d_ws + off);
  off += (size_t)D * H * sizeof(unsigned short);

  int* sure_ix = (int*)((char*)d_ws + off);       off += (size_t)B * S_MAX * sizeof(int);
  float* sure_val = (float*)((char*)d_ws + off);  off += (size_t)B * S_MAX * sizeof(float);
  int* sure_cnt = (int*)((char*)d_ws + off);      off += (size_t)B * sizeof(int);
  int* amb_ix = (int*)((char*)d_ws + off);        off += (size_t)B * A_MAX * sizeof(int);
  int* amb_cnt = (int*)((char*)d_ws + off);       off += (size_t)B * sizeof(int);
  const int useFAST = (off <= ws_size) ? 1 : 0;

  const bool fast_ok = (D % 64 == 0) && (D % 8 == 0) && (D <= D_MAX) &&
                       (H == H_FIX) && (B % 256 == 0);

  if (useFAST && fast_ok) {
    const size_t tx4 = (size_t)B * D / 4, tw4 = (size_t)H * D / 4;
    prep_xb<<<2048, 256, 0, stream>>>(x, b_pre, Xb, D, tx4);
    prep_wb<<<2048, 256, 0, stream>>>(W_enc, Wb, tw4);
    dim3 gg(H / 256, B / 256);
    enc_gemm_bf16<<<gg, 512, 0, stream>>>(Xb, Wb, b_enc, hidden, D, H);  // keys + 1st-half zero
    // delta >= 2*(GEMM err ~0.01 + bf16 ulp/2 ~0.008) with slack
    topk_classify_keys<<<B, 256, 0, stream>>>(hidden, sure_ix, sure_val, sure_cnt,
                                              amb_ix, amb_cnt, kptr, 0.05f);
    refine_scatter<<<B, 256, 0, stream>>>(x, b_pre, W_enc, b_enc,
                                          sure_ix, sure_val, sure_cnt,
                                          amb_ix, amb_cnt, kptr,
                                          hidden, tk_idx, tk_val, D);
    transpose_wdec_bf16<<<dim3((H + 31) / 32, (D + 31) / 32), 256, 0, stream>>>(W_dec, WTb, D, H);
    decode_loss2<<<B / 2, 256, 0, stream>>>(x, b_pre, b_dec, WTb,
                                            tk_idx, tk_val, kptr, recon, row_ssq, D);
  } else {
    dim3 gg(H / BN, B / BM);
    enc_gemm_f32<<<gg, 256, 0, stream>>>(x, W_enc, b_enc, b_pre, hidden, D, H);
    const size_t sh = CAND_MAX * sizeof(double) + (size_t)D * sizeof(float)
                    + CAND_MAX * sizeof(int) + (NBITER + 8) * sizeof(int);
    topk_refine<<<B, 256, sh, stream>>>(x, b_pre, W_enc, b_enc, hidden,
                                        tk_idx, tk_val, kptr, D, H, 1e-3f);
    decode_loss<<<B, 256, 0, stream>>>(x, b_pre, b_dec, W_dec,
                                       tk_idx, tk_val, kptr, recon, row_ssq, D, H);
  }

  const int rpb = (B + 63) / 64;
  finalize_part<<<64, 256, 0, stream>>>(row_ssq, tk_val, kptr, part_s, part_c, B, rpb);
  finalize_k2<<<1, 64, 0, stream>>>(part_s, part_c, scalars, 64, B, D);
}